// Round 1
// baseline (1101.992 us; speedup 1.0000x reference)
//
#include <hip/hip_runtime.h>

#define N_NODES 50000
#define N_EDGES 800000

typedef unsigned short u16;
typedef unsigned int u32;
typedef __attribute__((ext_vector_type(8))) short short8;
typedef __attribute__((ext_vector_type(4))) short s16x4;
typedef __attribute__((ext_vector_type(4))) float f32x4;

__device__ __forceinline__ u16 f2bf(float f) {
    union { float f; u32 u; } v; v.f = f;
    u32 r = v.u + 0x7FFFu + ((v.u >> 16) & 1u);
    return (u16)(r >> 16);
}

__device__ __forceinline__ float bf2f(u16 h) {
    union { u32 u; float f; } v; v.u = ((u32)h) << 16;
    return v.f;
}

// ---- Wc = Wg @ Wo (f32), bc = bg @ Wo ----
__global__ __launch_bounds__(256) void compute_wc(const float* __restrict__ Wg,
                                                  const float* __restrict__ bg,
                                                  const float* __restrict__ Wo,
                                                  float* __restrict__ Wc,
                                                  float* __restrict__ bc) {
    int b = blockIdx.x;
    if (b < 8) {
        for (int i = 0; i < 8; ++i) {
            int o = b * 2048 + i * 256 + threadIdx.x;
            int k = o >> 7, n = o & 127;
            float s = 0.f;
            for (int j = 0; j < 128; ++j) s += Wg[k * 128 + j] * Wo[j * 128 + n];
            Wc[o] = s;
        }
    } else if (threadIdx.x < 128) {
        int n = threadIdx.x;
        float s = 0.f;
        for (int j = 0; j < 128; ++j) s += bg[j] * Wo[j * 128 + n];
        bc[n] = s;
    }
}

// ---- weight pre-pack: [128x128] row-major f32 -> bf16 B-fragments ----
// tile t (16 cols), chunk c (32 k): lane holds B[k=c*32+(lane>>4)*8+j][n=t*16+(lane&15)]
// blocks 0-7: We[:128]->PB1(t0..7); 8-15: We[128:256]->PB1(t8..15); 16-23: We[256:]->PB3; 24-31: Wc->PBc
__global__ __launch_bounds__(256) void pack_all(const float* __restrict__ We,
                                                const float* __restrict__ Wc,
                                                const float* __restrict__ be,
                                                u16* __restrict__ PB1,
                                                u16* __restrict__ PB3,
                                                u16* __restrict__ PBc,
                                                float* __restrict__ b256) {
    int bid = blockIdx.x;
    int which = bid >> 3;
    const float* src;
    u16* dst;
    int tOff = 0;
    if (which == 0) { src = We; dst = PB1; }
    else if (which == 1) { src = We + 16384; dst = PB1; tOff = 8; }
    else if (which == 2) { src = We + 32768; dst = PB3; }
    else { src = Wc; dst = PBc; }
    int f = ((bid & 7) << 8) + threadIdx.x;
    int t = f >> 8, c = (f >> 6) & 3, lane = f & 63;
    int q = lane >> 4, n = lane & 15;
    const float* s = src + (size_t)(c * 32 + q * 8) * 128 + t * 16 + n;
    u16* dp = dst + ((((size_t)(t + tOff) * 4 + c) * 64 + lane) * 8);
#pragma unroll
    for (int j = 0; j < 8; ++j) dp[j] = f2bf(s[(size_t)j * 128]);
    if (bid == 0) b256[threadIdx.x] = (threadIdx.x < 128) ? be[threadIdx.x] : 0.f;
}

// ---- counting sort ----
__global__ __launch_bounds__(256) void hist_kernel(const int* __restrict__ srcIdx,
                                                   const int* __restrict__ dstIdx,
                                                   int* __restrict__ degD,
                                                   int* __restrict__ degS) {
    int e = blockIdx.x * 256 + threadIdx.x;
    if (e >= N_EDGES) return;
    atomicAdd(&degD[dstIdx[e]], 1);
    atomicAdd(&degS[srcIdx[e]], 1);
}

// 2 blocks, 256 threads each: block 0 scans degD, block 1 scans degS
__global__ __launch_bounds__(256) void scan_kernel(const int* __restrict__ degD,
                                                   const int* __restrict__ degS,
                                                   int* __restrict__ offD, int* __restrict__ curD,
                                                   int* __restrict__ offS, int* __restrict__ curS) {
    const int* deg = blockIdx.x ? degS : degD;
    int* off = blockIdx.x ? offS : offD;
    int* cur = blockIdx.x ? curS : curD;
    __shared__ int buf[256];
    const int CHUNK = 196;  // 256*196 = 50176 >= 50000
    int tid = threadIdx.x;
    int s0 = tid * CHUNK, s1 = s0 + CHUNK;
    if (s1 > N_NODES) s1 = N_NODES;
    int s = 0;
    for (int i = s0; i < s1; ++i) s += deg[i];
    buf[tid] = s;
    __syncthreads();
    for (int o = 1; o < 256; o <<= 1) {
        int v = (tid >= o) ? buf[tid - o] : 0;
        __syncthreads();
        buf[tid] += v;
        __syncthreads();
    }
    int run = (tid > 0) ? buf[tid - 1] : 0;
    for (int i = s0; i < s1; ++i) {
        off[i] = run;
        cur[i] = run;
        run += deg[i];
    }
    if (tid == 255) off[N_NODES] = buf[255];
}

__global__ __launch_bounds__(256) void scatter_kernel(const int* __restrict__ srcIdx,
                                                      const int* __restrict__ dstIdx,
                                                      int* __restrict__ curD,
                                                      int* __restrict__ curS,
                                                      int* __restrict__ sd_ea,
                                                      int* __restrict__ sd_src,
                                                      int* __restrict__ ss_dst) {
    int e = blockIdx.x * 256 + threadIdx.x;
    if (e >= N_EDGES) return;
    int s = srcIdx[e], d = dstIdx[e];
    int p = atomicAdd(&curD[d], 1);
    sd_ea[p] = e;
    sd_src[p] = s;
    int p2 = atomicAdd(&curS[s], 1);
    ss_dst[p2] = d;
}

// ---- GEMM: out[M,C] = A[M,128] @ B + bias (+ rowdeg*bias2 if flags&4).
// flags: 1=out bf16, 2=A bf16, 4=row-scaled second bias ----
__global__ __launch_bounds__(256) void gemm_mfma(const void* __restrict__ Ap,
                                                 const u16* __restrict__ PB,
                                                 const float* __restrict__ bias,
                                                 const float* __restrict__ bias2,
                                                 const int* __restrict__ rowdeg,
                                                 void* __restrict__ outp,
                                                 int M, int Ctiles, int flags) {
    int tid = threadIdx.x;
    int wave = tid >> 6;
    int lane = tid & 63;
    int strip = blockIdx.x * 4 + wave;
    int row0 = strip * 16;
    if (row0 >= M) return;
    int q = lane >> 4, n = lane & 15;
    int C = Ctiles * 16;

    short8 a[4];
    if (flags & 2) {
        const u16* ap = (const u16*)Ap + (size_t)(row0 + n) * 128 + q * 8;
#pragma unroll
        for (int c = 0; c < 4; ++c) a[c] = *(const short8*)(ap + c * 32);
    } else {
        const float* ap = (const float*)Ap + (size_t)(row0 + n) * 128 + q * 8;
#pragma unroll
        for (int c = 0; c < 4; ++c) {
            f32x4 f0 = *(const f32x4*)(ap + c * 32);
            f32x4 f1 = *(const f32x4*)(ap + c * 32 + 4);
            short8 t;
#pragma unroll
            for (int j = 0; j < 4; ++j) {
                t[j] = (short)f2bf(f0[j]);
                t[4 + j] = (short)f2bf(f1[j]);
            }
            a[c] = t;
        }
    }

    float rb[4] = {0.f, 0.f, 0.f, 0.f};
    if (flags & 4) {
#pragma unroll
        for (int r = 0; r < 4; ++r) rb[r] = (float)rowdeg[row0 + q * 4 + r];
    }

    for (int t = 0; t < Ctiles; ++t) {
        f32x4 acc = {0.f, 0.f, 0.f, 0.f};
#pragma unroll
        for (int c = 0; c < 4; ++c) {
            short8 b = *(const short8*)(PB + (((size_t)t * 4 + c) * 64 + lane) * 8);
            acc = __builtin_amdgcn_mfma_f32_16x16x32_bf16(a[c], b, acc, 0, 0, 0);
        }
        int col = t * 16 + n;
        float bv = bias ? bias[col] : 0.f;
        float b2 = (flags & 4) ? bias2[col] : 0.f;
#pragma unroll
        for (int r = 0; r < 4; ++r) {
            int row = row0 + q * 4 + r;
            float v = acc[r] + bv + rb[r] * b2;
            if (flags & 1)
                ((u16*)outp)[(size_t)row * C + col] = f2bf(v);
            else
                ((float*)outp)[(size_t)row * C + col] = v;
        }
    }
}

// ---- fused aggregation: one wave per dst node, edges sorted by dst ----
// agg[n] = sum_{e in seg(n)} silu( EA[e]@W3 + T1a[n] + T1b[src_e] )   (bf16 out)
// T1b[src] rows staged per 16-edge tile into wave-private LDS (stride 132 u16:
// read bank = 8q + 2r + 8t + n/2 -> all 32 banks, conflict-free).
__global__ __launch_bounds__(256) void agg_fused(const float* __restrict__ EA,
                                                 const u16* __restrict__ PB3,
                                                 const int* __restrict__ offD,
                                                 const int* __restrict__ sd_ea,
                                                 const int* __restrict__ sd_src,
                                                 const u16* __restrict__ T1,
                                                 u16* __restrict__ agg) {
    __shared__ u16 ldsT[4][16][132];
    int tid = threadIdx.x;
    int wave = tid >> 6;
    int lane = tid & 63;
    int node = blockIdx.x * 4 + wave;
    if (node >= N_NODES) return;
    int q = lane >> 4, n = lane & 15;
    int segS = offD[node], segE = offD[node + 1];

    float g1[8], rowAcc[8];
#pragma unroll
    for (int t = 0; t < 8; ++t) {
        g1[t] = bf2f(T1[(size_t)node * 256 + t * 16 + n]);
        rowAcc[t] = 0.f;
    }

    int rl = lane >> 2, cb = lane & 3;  // staging: row, 16B-chunk
    u16* myL = &ldsT[wave][0][0];

    for (int base = segS; base < segE; base += 16) {
        int er = base + n;
        if (er > segE - 1) er = segE - 1;  // clamp: duplicate row, masked below
        const float* ap = EA + (size_t)sd_ea[er] * 128 + q * 8;
        short8 a[4];
#pragma unroll
        for (int c = 0; c < 4; ++c) {
            f32x4 f0 = *(const f32x4*)(ap + c * 32);
            f32x4 f1 = *(const f32x4*)(ap + c * 32 + 4);
            short8 t;
#pragma unroll
            for (int j = 0; j < 4; ++j) {
                t[j] = (short)f2bf(f0[j]);
                t[4 + j] = (short)f2bf(f1[j]);
            }
            a[c] = t;
        }

        // stage the 16 T1b[src] rows into LDS (vector global loads, wave-local)
        int erL = base + rl;
        if (erL > segE - 1) erL = segE - 1;
        const u16* tb = T1 + (size_t)sd_src[erL] * 256 + 128;
        asm volatile("s_waitcnt lgkmcnt(0)" ::: "memory");  // prior-iter reads done
#pragma unroll
        for (int i = 0; i < 4; ++i) {
            short8 v = *(const short8*)(tb + (i * 4 + cb) * 8);
            s16x4 lo = __builtin_shufflevector(v, v, 0, 1, 2, 3);
            s16x4 hi = __builtin_shufflevector(v, v, 4, 5, 6, 7);
            *(s16x4*)(myL + rl * 132 + (i * 4 + cb) * 8) = lo;
            *(s16x4*)(myL + rl * 132 + (i * 4 + cb) * 8 + 4) = hi;
        }
        asm volatile("s_waitcnt lgkmcnt(0)" ::: "memory");  // writes visible to wave

        bool val[4];
#pragma unroll
        for (int r = 0; r < 4; ++r) val[r] = (base + q * 4 + r) < segE;

#pragma unroll
        for (int t = 0; t < 8; ++t) {
            f32x4 acc = {0.f, 0.f, 0.f, 0.f};
#pragma unroll
            for (int c = 0; c < 4; ++c) {
                short8 b = *(const short8*)(PB3 + (((size_t)t * 4 + c) * 64 + lane) * 8);
                acc = __builtin_amdgcn_mfma_f32_16x16x32_bf16(a[c], b, acc, 0, 0, 0);
            }
#pragma unroll
            for (int r = 0; r < 4; ++r) {
                float v = acc[r] + g1[t] + bf2f(myL[(q * 4 + r) * 132 + t * 16 + n]);
                float m = v * __builtin_amdgcn_rcpf(1.f + __expf(-v));  // SiLU
                rowAcc[t] += val[r] ? m : 0.f;
            }
        }
    }
    // reduce over the 4 quads (rows) -> full column sums
#pragma unroll
    for (int t = 0; t < 8; ++t) {
        float v = rowAcc[t];
        v += __shfl_xor(v, 16, 64);
        v += __shfl_xor(v, 32, 64);
        if (lane < 16) agg[(size_t)node * 128 + t * 16 + lane] = f2bf(v);
    }
}

// ---- attention sum: one wave per src node, edges sorted by src ----
// G[n] = sum_{e in segS(n)} agg[dst_e]   (bf16 in -> f32 out)
// half-waves each own an edge (32 lanes x 8B = full 256B row), 4-deep unroll.
__global__ __launch_bounds__(256) void attn_gather(const int* __restrict__ offS,
                                                   const int* __restrict__ ss_dst,
                                                   const u16* __restrict__ hsrc,
                                                   float* __restrict__ attn) {
    int tid = threadIdx.x;
    int wave = tid >> 6;
    int lane = tid & 63;
    int node = blockIdx.x * 4 + wave;
    if (node >= N_NODES) return;
    int e0 = offS[node], e1 = offS[node + 1];
    int half = lane >> 5;
    int l = lane & 31;
    float a0 = 0.f, a1 = 0.f, a2 = 0.f, a3 = 0.f;
    int e = e0 + half;
    for (; e + 6 < e1; e += 8) {
        int d0 = ss_dst[e], d1 = ss_dst[e + 2], d2 = ss_dst[e + 4], d3 = ss_dst[e + 6];
        uint2 h0 = *(const uint2*)(hsrc + (size_t)d0 * 128 + l * 4);
        uint2 h1 = *(const uint2*)(hsrc + (size_t)d1 * 128 + l * 4);
        uint2 h2 = *(const uint2*)(hsrc + (size_t)d2 * 128 + l * 4);
        uint2 h3 = *(const uint2*)(hsrc + (size_t)d3 * 128 + l * 4);
        a0 += bf2f((u16)(h0.x & 0xFFFFu)) + bf2f((u16)(h1.x & 0xFFFFu)) +
              bf2f((u16)(h2.x & 0xFFFFu)) + bf2f((u16)(h3.x & 0xFFFFu));
        a1 += bf2f((u16)(h0.x >> 16)) + bf2f((u16)(h1.x >> 16)) +
              bf2f((u16)(h2.x >> 16)) + bf2f((u16)(h3.x >> 16));
        a2 += bf2f((u16)(h0.y & 0xFFFFu)) + bf2f((u16)(h1.y & 0xFFFFu)) +
              bf2f((u16)(h2.y & 0xFFFFu)) + bf2f((u16)(h3.y & 0xFFFFu));
        a3 += bf2f((u16)(h0.y >> 16)) + bf2f((u16)(h1.y >> 16)) +
              bf2f((u16)(h2.y >> 16)) + bf2f((u16)(h3.y >> 16));
    }
    for (; e < e1; e += 2) {
        int d = ss_dst[e];
        uint2 hv = *(const uint2*)(hsrc + (size_t)d * 128 + l * 4);
        a0 += bf2f((u16)(hv.x & 0xFFFFu));
        a1 += bf2f((u16)(hv.x >> 16));
        a2 += bf2f((u16)(hv.y & 0xFFFFu));
        a3 += bf2f((u16)(hv.y >> 16));
    }
    a0 += __shfl_xor(a0, 32, 64);
    a1 += __shfl_xor(a1, 32, 64);
    a2 += __shfl_xor(a2, 32, 64);
    a3 += __shfl_xor(a3, 32, 64);
    if (half == 0) {
        f32x4 o;
        o[0] = a0; o[1] = a1; o[2] = a2; o[3] = a3;
        *(f32x4*)(attn + (size_t)node * 128 + l * 4) = o;
    }
}

extern "C" void kernel_launch(void* const* d_in, const int* in_sizes, int n_in,
                              void* d_out, int out_size, void* d_ws, size_t ws_size,
                              hipStream_t stream) {
    const float* x  = (const float*)d_in[0];
    const int* ei   = (const int*)d_in[1];
    const float* ea = (const float*)d_in[2];
    const float* We = (const float*)d_in[3];
    const float* be = (const float*)d_in[4];
    const float* Wg = (const float*)d_in[5];
    const float* bg = (const float*)d_in[6];
    // d_in[7]=Wa, d_in[8]=ba: dead — softmax over a size-1 axis is identically 1
    const float* Wo = (const float*)d_in[9];
    const float* bo = (const float*)d_in[10];
    float* out = (float*)d_out;

    const int* srcIdx = ei;            // edge_index[0]
    const int* dstIdx = ei + N_EDGES;  // edge_index[1]

    char* ws = (char*)d_ws;
    u16*   PB1     = (u16*)(ws + 0);          // 64 KiB  [W1|W2] 16 tiles
    u16*   PB3     = (u16*)(ws + 65536);      // 32 KiB
    u16*   PBc     = (u16*)(ws + 98304);      // 32 KiB  (packed Wg@Wo)
    float* Wc      = (float*)(ws + 131072);   // 64 KiB f32
    float* bias256 = (float*)(ws + 196608);   // 1 KiB
    float* bc      = (float*)(ws + 197632);   // 512 B (bg@Wo)
    u16*   T1      = (u16*)(ws + 262144);     // [N,256] bf16, 25.6 MB
    float* attn    = (float*)(ws + 262144);   // alias: T1 dead after agg_fused
    u16*   agg     = (u16*)(ws + 25862144);   // [N,128] bf16, 12.8 MB
    int*   degD    = (int*)(ws + 51462144);   // 200 KB
    int*   degS    = (int*)(ws + 51662144);   // 200 KB
    int*   offD    = (int*)(ws + 51862144);   // 200 KB (+pad)
    int*   offS    = (int*)(ws + 52062160);
    int*   curD    = (int*)(ws + 52262176);
    int*   curS    = (int*)(ws + 52462176);
    int*   sd_ea   = (int*)(ws + 52662176);   // 3.2 MB: edge id, sorted by dst
    int*   sd_src  = (int*)(ws + 55862176);   // 3.2 MB: src,    sorted by dst
    int*   ss_dst  = (int*)(ws + 59062176);   // 3.2 MB: dst,    sorted by src

    hipMemsetAsync(degD, 0, 400000, stream);  // degD + degS (contiguous)

    compute_wc<<<9, 256, 0, stream>>>(Wg, bg, Wo, Wc, bc);
    pack_all<<<32, 256, 0, stream>>>(We, Wc, be, PB1, PB3, PBc, bias256);

    // counting sorts: by dst (agg) and by src (attn)
    hist_kernel<<<3125, 256, 0, stream>>>(srcIdx, dstIdx, degD, degS);
    scan_kernel<<<2, 256, 0, stream>>>(degD, degS, offD, curD, offS, curS);
    scatter_kernel<<<3125, 256, 0, stream>>>(srcIdx, dstIdx, curD, curS, sd_ea, sd_src, ss_dst);

    // T1 = [x@W1 + be | x@W2]  (bf16)
    gemm_mfma<<<782, 256, 0, stream>>>(x, PB1, bias256, nullptr, nullptr, T1, N_NODES, 16, 1);

    // agg[n] = sum over dst-segment of silu(...)  — no atomics
    agg_fused<<<12500, 256, 0, stream>>>(ea, PB3, offD, sd_ea, sd_src, T1, agg);

    // G[n] = sum over src-segment of agg[dst]  (h-GEMM folded away; writes over T1)
    attn_gather<<<12500, 256, 0, stream>>>(offS, ss_dst, agg, attn);

    // out = G@(Wg@Wo) + degS*(bg@Wo) + bo  (f32)
    gemm_mfma<<<782, 256, 0, stream>>>(attn, PBc, bo, bc, degS, out, N_NODES, 8, 4);

    (void)in_sizes; (void)n_in; (void)out_size; (void)ws_size;
}